// Round 16
// baseline (148.246 us; speedup 1.0000x reference)
//
#include <hip/hip_runtime.h>
#include <stdint.h>

// Problem constants
constexpr int CXR = 15, ECG = 14, EHR = 13;
constexpr int TOTAL = 42;
constexpr int MPITCH = 44;
constexpr float LN_EPS = 1e-5f;

// Workspace layout (float offsets)
constexpr int WS_B    = 1848;                 // fused bias (42)
constexpr int WS_G    = WS_B + TOTAL;         // ln gamma (42)
constexpr int WS_BETA = WS_G + TOTAL;         // ln beta  (42)
constexpr int WS_FRAG = 1976;                 // fp16 B-fragments (16B aligned)

// Tiling: 64 rows per wave, 2 waves per block, one-shot (r7/r15-proven)
constexpr int WROWS = 64;
constexpr int ARENA_B = 11264;                // per-wave LDS arena (bytes)
constexpr int S0F = 0, S1F = WROWS * CXR, S2F = S1F + WROWS * ECG;  // 0,960,1856
constexpr int WC0 = WROWS * CXR / 4, WC1 = WROWS * ECG / 4, WC2 = WROWS * EHR / 4;

typedef _Float16 half8 __attribute__((ext_vector_type(8)));
typedef float float4v __attribute__((ext_vector_type(4)));

struct FuseArgs {
    const float *in_w, *in_b, *out_w, *out_b, *kv_w, *kv_b, *ln_g, *ln_b;
    int E, R;
};

// Merged fuse kernel (r15-proven): block m computes its segment's A_eff in
// shared, writes bias/gamma/beta, then emits W' fp16 B-fragments with the
// verified k-packing: W[k][col] = A_eff[col][k] (+ identity at k==col, bias
// row at k==42). Frag elem i <-> k = t*32 + 8*(lane>>4) + i.
__global__ void fuse_all_kernel(FuseArgs a0, FuseArgs a1, FuseArgs a2,
                                float* __restrict__ ws) {
    const int m = blockIdx.x;
    FuseArgs a = (m == 0) ? a0 : (m == 1 ? a1 : a2);
    const int E = a.E, R = a.R;
    const int tid = threadIdx.x;

    __shared__ float T1[15 * 42];
    __shared__ float b1[15];
    __shared__ float A[15 * 42];      // A_eff rows of this segment
    __shared__ float beff[15];        // fused bias of this segment

    for (int idx = tid; idx < E * TOTAL; idx += blockDim.x) {
        int i = idx / TOTAL, j = idx % TOTAL;
        float acc = 0.f;
        for (int k = 0; k < E; ++k)
            acc = fmaf(a.in_w[(2 * E + i) * E + k], a.kv_w[k * TOTAL + j], acc);
        T1[i * TOTAL + j] = acc;
    }
    if (tid < E) {
        float acc = a.in_b[2 * E + tid];
        for (int k = 0; k < E; ++k)
            acc = fmaf(a.in_w[(2 * E + tid) * E + k], a.kv_b[k], acc);
        b1[tid] = acc;
    }
    __syncthreads();

    for (int idx = tid; idx < E * TOTAL; idx += blockDim.x) {
        int i = idx / TOTAL, j = idx % TOTAL;
        float acc = 0.f;
        for (int k = 0; k < E; ++k)
            acc = fmaf(a.out_w[i * E + k], T1[k * TOTAL + j], acc);
        A[i * TOTAL + j] = acc;
    }
    if (tid < E) {
        float acc = a.out_b[tid];
        for (int k = 0; k < E; ++k)
            acc = fmaf(a.out_w[tid * E + k], b1[k], acc);
        beff[tid]             = acc;
        ws[WS_B + R + tid]    = acc;
        ws[WS_G + R + tid]    = a.ln_g[tid];
        ws[WS_BETA + R + tid] = a.ln_b[tid];
    }
    __syncthreads();

    if (tid < 128) {
        const int l = tid & 63, t = tid >> 6;
        const int k0 = t * 32 + 8 * (l >> 4);
#pragma unroll
        for (int n = 0; n < 3; ++n) {
            const int c = n * 16 + (l & 15);
            const int j = c - R;                 // local feature
            const bool mine = (j >= 0 && j < E);
            const bool pad  = (c >= TOTAL) && (m == 2);   // cols 42..47
            if (!mine && !pad) continue;
            half8 h;
#pragma unroll
            for (int i = 0; i < 8; ++i) {
                int k = k0 + i;
                float v = 0.f;
                if (mine) {
                    if (k < TOTAL) {
                        v = A[j * TOTAL + k];
                        if (k == c) v += 1.f;     // residual identity
                    } else if (k == TOTAL) {
                        v = beff[j];              // bias via x[42]=1.0
                    }
                }
                h[i] = (_Float16)v;
            }
            ((half8*)(ws + WS_FRAG))[(n * 2 + t) * 64 + l] = h;
        }
    }
}

// Async global->LDS staging (linear, width 16) — exactly 4 VMEM insts each.
template <int CH>
__device__ __forceinline__ void stage_wave(const float* __restrict__ g,
                                           float* lds_seg_base, int lane) {
#pragma unroll
    for (int it = 0; it < (CH + 63) / 64; ++it) {
        int idx = lane + it * 64;
        if (idx < CH) {
            const __attribute__((address_space(1))) void* src =
                (const __attribute__((address_space(1))) void*)
                    ((const char*)g + (size_t)idx * 16);
            __attribute__((address_space(3))) void* dst =
                (__attribute__((address_space(3))) void*)
                    ((char*)lds_seg_base + it * 1024);
            __builtin_amdgcn_global_load_lds(src, dst, 16, 0, 0);
        }
    }
}

// cmca_main: r15 body with counted-vmcnt phased gathers (T4).
__global__ __launch_bounds__(128) void cmca_main(
        const float* __restrict__ cxr, const float* __restrict__ ecg,
        const float* __restrict__ ehr, const float* __restrict__ ws,
        float* __restrict__ out_cxr, float* __restrict__ out_ecg,
        float* __restrict__ out_ehr) {
    __shared__ __align__(16) char smem[2 * ARENA_B];
    const int tid = threadIdx.x;
    const int w = tid >> 6, lane = tid & 63;
    char* arena = smem + w * ARENA_B;
    float* af = (float*)arena;
    const size_t gw = (size_t)blockIdx.x * 2 + w;

    // ---- stage all three segments (12 DMA loads, in-order retire) ----
    stage_wave<WC0>(cxr + gw * (size_t)(WROWS * CXR), af + S0F, lane);  // 4
    stage_wave<WC1>(ecg + gw * (size_t)(WROWS * ECG), af + S1F, lane);  // 4
    stage_wave<WC2>(ehr + gw * (size_t)(WROWS * EHR), af + S2F, lane);  // 4

    // ---- phased gather: wait only for the segment about to be read ----
    float x[TOTAL];
    asm volatile("s_waitcnt vmcnt(8)" ::: "memory");   // seg0's 4 retired
#pragma unroll
    for (int j = 0; j < CXR; ++j) x[j] = af[S0F + lane * CXR + j];
    asm volatile("s_waitcnt vmcnt(4)" ::: "memory");   // seg1 retired
#pragma unroll
    for (int j = 0; j < ECG; ++j) x[CXR + j] = af[S1F + lane * ECG + j];
    asm volatile("s_waitcnt vmcnt(0)" ::: "memory");   // seg2 retired
#pragma unroll
    for (int j = 0; j < EHR; ++j) x[CXR + ECG + j] = af[S2F + lane * EHR + j];
    __builtin_amdgcn_sched_barrier(0);

    // ---- B-fragments (6 x 16B, L2-hot; latency hides under tile build) ----
    const half8* fr = (const half8*)(ws + WS_FRAG);
    half8 bfrag[6];
#pragma unroll
    for (int q = 0; q < 6; ++q) bfrag[q] = fr[q * 64 + lane];

    // ---- write fp16 X row [64 halfs], swizzled; x[42]=1.0, pad=0 ----
    {
        const int swz = (lane & 7) << 4;
#pragma unroll
        for (int j = 0; j < 8; ++j) {
            half8 h;
#pragma unroll
            for (int e = 0; e < 8; ++e) {
                int idx = j * 8 + e;
                float v = (idx < TOTAL) ? x[idx] : (idx == TOTAL ? 1.f : 0.f);
                h[e] = (_Float16)v;
            }
            *(half8*)(arena + ((lane * 128 + j * 16) ^ swz)) = h;
        }
    }
    __builtin_amdgcn_sched_barrier(0);

    // ---- read A-fragments (one b128 per m,t) ----
    half8 afr[4][2];
#pragma unroll
    for (int m = 0; m < 4; ++m) {
        int row = m * 16 + (lane & 15);
        int rswz = (row & 7) << 4;
#pragma unroll
        for (int t = 0; t < 2; ++t)
            afr[m][t] = *(const half8*)(arena +
                ((row * 128 + t * 64 + (lane >> 4) * 16) ^ rswz));
    }
    __builtin_amdgcn_sched_barrier(0);

    // ---- 24 MFMAs: Y[64x48] = X[64x64] * W[64x48] ----
    float4v acc[4][3];
#pragma unroll
    for (int m = 0; m < 4; ++m)
#pragma unroll
        for (int n = 0; n < 3; ++n) acc[m][n] = float4v{0.f, 0.f, 0.f, 0.f};
#pragma unroll
    for (int t = 0; t < 2; ++t)
#pragma unroll
        for (int m = 0; m < 4; ++m)
#pragma unroll
            for (int n = 0; n < 3; ++n)
                acc[m][n] = __builtin_amdgcn_mfma_f32_16x16x32_f16(
                    afr[m][t], bfrag[n * 2 + t], acc[m][n], 0, 0, 0);

    // ---- scatter y to [row][44] f32 tile ----
    __builtin_amdgcn_sched_barrier(0);
#pragma unroll
    for (int m = 0; m < 4; ++m)
#pragma unroll
        for (int n = 0; n < 3; ++n)
#pragma unroll
            for (int r = 0; r < 4; ++r) {
                int row = m * 16 + (lane >> 4) * 4 + r;
                int col = n * 16 + (lane & 15);
                if (col < MPITCH) af[row * MPITCH + col] = acc[m][n][r];
            }
    __builtin_amdgcn_sched_barrier(0);

    // ---- epilogue (lane = row): gather y, per-segment LN, compact write ----
    float y[MPITCH];
#pragma unroll
    for (int j = 0; j < 11; ++j) {
        float4v q = *(const float4v*)(af + lane * MPITCH + j * 4);
        y[j * 4 + 0] = q[0]; y[j * 4 + 1] = q[1];
        y[j * 4 + 2] = q[2]; y[j * 4 + 3] = q[3];
    }
    __builtin_amdgcn_sched_barrier(0);

    float res[TOTAL];
    {
#define LN_SEG(S, E)                                                       \
        {                                                                  \
            float mu = 0.f;                                                \
            _Pragma("unroll")                                              \
            for (int i = 0; i < (E); ++i) mu += y[(S) + i];                \
            mu *= (1.0f / (E));                                            \
            float var = 0.f;                                               \
            _Pragma("unroll")                                              \
            for (int i = 0; i < (E); ++i) {                                \
                float d = y[(S) + i] - mu; var = fmaf(d, d, var);          \
            }                                                              \
            var *= (1.0f / (E));                                           \
            float rs = rsqrtf(var + LN_EPS);                               \
            _Pragma("unroll")                                              \
            for (int i = 0; i < (E); ++i) {                                \
                float nv = (y[(S) + i] - mu) * rs;                         \
                res[(S) + i] = fmaf(nv, ws[WS_G + (S) + i],                \
                                    ws[WS_BETA + (S) + i]);                \
            }                                                              \
        }
        LN_SEG(0, CXR)
        LN_SEG(CXR, ECG)
        LN_SEG(CXR + ECG, EHR)
#undef LN_SEG
    }
#pragma unroll
    for (int j = 0; j < CXR; ++j) af[S0F + lane * CXR + j] = res[j];
#pragma unroll
    for (int j = 0; j < ECG; ++j) af[S1F + lane * ECG + j] = res[CXR + j];
#pragma unroll
    for (int j = 0; j < EHR; ++j) af[S2F + lane * EHR + j] = res[CXR + ECG + j];
    __builtin_amdgcn_sched_barrier(0);

    // ---- coalesced float4 stores ----
    const float4v* wb4 = (const float4v*)af;
    float4v* o0 = (float4v*)(out_cxr + gw * (size_t)(WROWS * CXR));
    float4v* o1 = (float4v*)(out_ecg + gw * (size_t)(WROWS * ECG));
    float4v* o2 = (float4v*)(out_ehr + gw * (size_t)(WROWS * EHR));
#pragma unroll
    for (int it = 0; it < 4; ++it) {
        int idx = lane + it * 64;
        if (idx < WC0) o0[idx] = wb4[idx];
    }
#pragma unroll
    for (int it = 0; it < 4; ++it) {
        int idx = lane + it * 64;
        if (idx < WC1) o1[idx] = wb4[WC0 + idx];
    }
#pragma unroll
    for (int it = 0; it < 4; ++it) {
        int idx = lane + it * 64;
        if (idx < WC2) o2[idx] = wb4[WC0 + WC1 + idx];
    }
}

extern "C" void kernel_launch(void* const* d_in, const int* in_sizes, int n_in,
                              void* d_out, int out_size, void* d_ws, size_t ws_size,
                              hipStream_t stream) {
    const float* cxr = (const float*)d_in[0];
    const float* ecg = (const float*)d_in[1];
    const float* ehr = (const float*)d_in[2];
    float* ws = (float*)d_ws;
    float* out = (float*)d_out;

    const size_t Bn = (size_t)in_sizes[0] / CXR;   // 2097152

    auto mk = [&](int base, int E, int R) {
        FuseArgs a;
        a.in_w  = (const float*)d_in[base + 0];
        a.in_b  = (const float*)d_in[base + 1];
        a.out_w = (const float*)d_in[base + 2];
        a.out_b = (const float*)d_in[base + 3];
        a.kv_w  = (const float*)d_in[base + 4];
        a.kv_b  = (const float*)d_in[base + 5];
        a.ln_g  = (const float*)d_in[base + 6];
        a.ln_b  = (const float*)d_in[base + 7];
        a.E = E; a.R = R;
        return a;
    };
    FuseArgs a0 = mk(3, CXR, 0);
    FuseArgs a1 = mk(11, ECG, CXR);
    FuseArgs a2 = mk(19, EHR, CXR + ECG);

    fuse_all_kernel<<<3, 256, 0, stream>>>(a0, a1, a2, ws);

    const int nblocks = (int)(Bn / (WROWS * 2));   // 16384 blocks x 2 waves
    cmca_main<<<nblocks, 128, 0, stream>>>(cxr, ecg, ehr, ws,
                                           out,
                                           out + Bn * CXR,
                                           out + Bn * (CXR + ECG));
}

// Round 17
// 145.841 us; speedup vs baseline: 1.0165x; 1.0165x over previous
//
#include <hip/hip_runtime.h>
#include <stdint.h>

// Problem constants
constexpr int CXR = 15, ECG = 14, EHR = 13;
constexpr int TOTAL = 42;
constexpr int MPITCH = 44;
constexpr float LN_EPS = 1e-5f;

// Workspace layout (float offsets)
constexpr int WS_B    = 1848;                 // fused bias (42)
constexpr int WS_G    = WS_B + TOTAL;         // ln gamma (42)
constexpr int WS_BETA = WS_G + TOTAL;         // ln beta  (42)
constexpr int WS_FRAG = 1976;                 // fp16 B-fragments (16B aligned)

// Tiling: 64 rows per wave, 2 waves per block, one-shot (r15-proven)
constexpr int WROWS = 64;
constexpr int ARENA_B = 11264;                // per-wave LDS arena (bytes)
constexpr int S0F = 0, S1F = WROWS * CXR, S2F = S1F + WROWS * ECG;  // 0,960,1856
constexpr int WC0 = WROWS * CXR / 4, WC1 = WROWS * ECG / 4, WC2 = WROWS * EHR / 4;

typedef _Float16 half8 __attribute__((ext_vector_type(8)));
typedef float float4v __attribute__((ext_vector_type(4)));
typedef float f4a __attribute__((ext_vector_type(4), aligned(4)));  // dword-aligned

struct FuseArgs {
    const float *in_w, *in_b, *out_w, *out_b, *kv_w, *kv_b, *ln_g, *ln_b;
    int E, R;
};

// Merged fuse kernel (r15-proven, unchanged): block m computes its segment's
// A_eff in shared, writes bias/gamma/beta, then emits W' fp16 B-fragments.
// W[k][col] = A_eff[col][k] (+ identity at k==col, bias row at k==42).
// Frag elem i <-> k = t*32 + 8*(lane>>4) + i.
__global__ void fuse_all_kernel(FuseArgs a0, FuseArgs a1, FuseArgs a2,
                                float* __restrict__ ws) {
    const int m = blockIdx.x;
    FuseArgs a = (m == 0) ? a0 : (m == 1 ? a1 : a2);
    const int E = a.E, R = a.R;
    const int tid = threadIdx.x;

    __shared__ float T1[15 * 42];
    __shared__ float b1[15];
    __shared__ float A[15 * 42];
    __shared__ float beff[15];

    for (int idx = tid; idx < E * TOTAL; idx += blockDim.x) {
        int i = idx / TOTAL, j = idx % TOTAL;
        float acc = 0.f;
        for (int k = 0; k < E; ++k)
            acc = fmaf(a.in_w[(2 * E + i) * E + k], a.kv_w[k * TOTAL + j], acc);
        T1[i * TOTAL + j] = acc;
    }
    if (tid < E) {
        float acc = a.in_b[2 * E + tid];
        for (int k = 0; k < E; ++k)
            acc = fmaf(a.in_w[(2 * E + tid) * E + k], a.kv_b[k], acc);
        b1[tid] = acc;
    }
    __syncthreads();

    for (int idx = tid; idx < E * TOTAL; idx += blockDim.x) {
        int i = idx / TOTAL, j = idx % TOTAL;
        float acc = 0.f;
        for (int k = 0; k < E; ++k)
            acc = fmaf(a.out_w[i * E + k], T1[k * TOTAL + j], acc);
        A[i * TOTAL + j] = acc;
    }
    if (tid < E) {
        float acc = a.out_b[tid];
        for (int k = 0; k < E; ++k)
            acc = fmaf(a.out_w[tid * E + k], b1[k], acc);
        beff[tid]             = acc;
        ws[WS_B + R + tid]    = acc;
        ws[WS_G + R + tid]    = a.ln_g[tid];
        ws[WS_BETA + R + tid] = a.ln_b[tid];
    }
    __syncthreads();

    if (tid < 128) {
        const int l = tid & 63, t = tid >> 6;
        const int k0 = t * 32 + 8 * (l >> 4);
#pragma unroll
        for (int n = 0; n < 3; ++n) {
            const int c = n * 16 + (l & 15);
            const int j = c - R;
            const bool mine = (j >= 0 && j < E);
            const bool pad  = (c >= TOTAL) && (m == 2);
            if (!mine && !pad) continue;
            half8 h;
#pragma unroll
            for (int i = 0; i < 8; ++i) {
                int k = k0 + i;
                float v = 0.f;
                if (mine) {
                    if (k < TOTAL) {
                        v = A[j * TOTAL + k];
                        if (k == c) v += 1.f;
                    } else if (k == TOTAL) {
                        v = beff[j];
                    }
                }
                h[i] = (_Float16)v;
            }
            ((half8*)(ws + WS_FRAG))[(n * 2 + t) * 64 + l] = h;
        }
    }
}

// cmca_main: r15 body, with the DMA-stage + vmcnt(0) + 42-ds_read gather
// replaced by 12 direct within-row vector loads (lane reads its OWN row).
__global__ __launch_bounds__(128) void cmca_main(
        const float* __restrict__ cxr, const float* __restrict__ ecg,
        const float* __restrict__ ehr, const float* __restrict__ ws,
        float* __restrict__ out_cxr, float* __restrict__ out_ecg,
        float* __restrict__ out_ehr) {
    __shared__ __align__(16) char smem[2 * ARENA_B];
    const int tid = threadIdx.x;
    const int w = tid >> 6, lane = tid & 63;
    char* arena = smem + w * ARENA_B;
    float* af = (float*)arena;
    const size_t gw = (size_t)blockIdx.x * 2 + w;

    // ---- B-fragments (6 x 16B coalesced, L2-hot) ----
    const half8* fr = (const half8*)(ws + WS_FRAG);
    half8 bfrag[6];
#pragma unroll
    for (int q = 0; q < 6; ++q) bfrag[q] = fr[q * 64 + lane];

    // ---- direct per-row loads: 12 within-row f4a (wave spans contiguous
    //      3840 B per segment; overlapping tail loads are L1-hot) ----
    const float* r0 = cxr + (gw * WROWS + lane) * (size_t)CXR;
    const float* r1 = ecg + (gw * WROWS + lane) * (size_t)ECG;
    const float* r2 = ehr + (gw * WROWS + lane) * (size_t)EHR;
    f4a v0a = *(const f4a*)(r0 + 0);
    f4a v0b = *(const f4a*)(r0 + 4);
    f4a v0c = *(const f4a*)(r0 + 8);
    f4a v0d = *(const f4a*)(r0 + 11);   // floats 11..14
    f4a v1a = *(const f4a*)(r1 + 0);
    f4a v1b = *(const f4a*)(r1 + 4);
    f4a v1c = *(const f4a*)(r1 + 8);    // floats 8..11 (use 8,9)
    f4a v1d = *(const f4a*)(r1 + 10);   // floats 10..13
    f4a v2a = *(const f4a*)(r2 + 0);
    f4a v2b = *(const f4a*)(r2 + 4);
    f4a v2c = *(const f4a*)(r2 + 8);    // floats 8..11 (use 8)
    f4a v2d = *(const f4a*)(r2 + 9);    // floats 9..12

    float x[TOTAL];
#pragma unroll
    for (int e = 0; e < 4; ++e) { x[e] = v0a[e]; x[4 + e] = v0b[e]; x[8 + e] = v0c[e]; }
    x[12] = v0d[1]; x[13] = v0d[2]; x[14] = v0d[3];
#pragma unroll
    for (int e = 0; e < 4; ++e) { x[15 + e] = v1a[e]; x[19 + e] = v1b[e]; }
    x[23] = v1c[0]; x[24] = v1c[1];
#pragma unroll
    for (int e = 0; e < 4; ++e) x[25 + e] = v1d[e];
#pragma unroll
    for (int e = 0; e < 4; ++e) { x[29 + e] = v2a[e]; x[33 + e] = v2b[e]; }
    x[37] = v2c[0];
#pragma unroll
    for (int e = 0; e < 4; ++e) x[38 + e] = v2d[e];
    __builtin_amdgcn_sched_barrier(0);

    // ---- write fp16 X row [64 halfs], swizzled; x[42]=1.0, pad=0 ----
    {
        const int swz = (lane & 7) << 4;
#pragma unroll
        for (int j = 0; j < 8; ++j) {
            half8 h;
#pragma unroll
            for (int e = 0; e < 8; ++e) {
                int idx = j * 8 + e;
                float v = (idx < TOTAL) ? x[idx] : (idx == TOTAL ? 1.f : 0.f);
                h[e] = (_Float16)v;
            }
            *(half8*)(arena + ((lane * 128 + j * 16) ^ swz)) = h;
        }
    }
    __builtin_amdgcn_sched_barrier(0);

    // ---- read A-fragments (one b128 per m,t) ----
    half8 afr[4][2];
#pragma unroll
    for (int m = 0; m < 4; ++m) {
        int row = m * 16 + (lane & 15);
        int rswz = (row & 7) << 4;
#pragma unroll
        for (int t = 0; t < 2; ++t)
            afr[m][t] = *(const half8*)(arena +
                ((row * 128 + t * 64 + (lane >> 4) * 16) ^ rswz));
    }
    __builtin_amdgcn_sched_barrier(0);

    // ---- 24 MFMAs: Y[64x48] = X[64x64] * W[64x48] ----
    float4v acc[4][3];
#pragma unroll
    for (int m = 0; m < 4; ++m)
#pragma unroll
        for (int n = 0; n < 3; ++n) acc[m][n] = float4v{0.f, 0.f, 0.f, 0.f};
#pragma unroll
    for (int t = 0; t < 2; ++t)
#pragma unroll
        for (int m = 0; m < 4; ++m)
#pragma unroll
            for (int n = 0; n < 3; ++n)
                acc[m][n] = __builtin_amdgcn_mfma_f32_16x16x32_f16(
                    afr[m][t], bfrag[n * 2 + t], acc[m][n], 0, 0, 0);

    // ---- scatter y to [row][44] f32 tile ----
    __builtin_amdgcn_sched_barrier(0);
#pragma unroll
    for (int m = 0; m < 4; ++m)
#pragma unroll
        for (int n = 0; n < 3; ++n)
#pragma unroll
            for (int r = 0; r < 4; ++r) {
                int row = m * 16 + (lane >> 4) * 4 + r;
                int col = n * 16 + (lane & 15);
                if (col < MPITCH) af[row * MPITCH + col] = acc[m][n][r];
            }
    __builtin_amdgcn_sched_barrier(0);

    // ---- epilogue (lane = row): gather y, per-segment LN, compact write ----
    float y[MPITCH];
#pragma unroll
    for (int j = 0; j < 11; ++j) {
        float4v q = *(const float4v*)(af + lane * MPITCH + j * 4);
        y[j * 4 + 0] = q[0]; y[j * 4 + 1] = q[1];
        y[j * 4 + 2] = q[2]; y[j * 4 + 3] = q[3];
    }
    __builtin_amdgcn_sched_barrier(0);

    float res[TOTAL];
    {
#define LN_SEG(S, E)                                                       \
        {                                                                  \
            float mu = 0.f;                                                \
            _Pragma("unroll")                                              \
            for (int i = 0; i < (E); ++i) mu += y[(S) + i];                \
            mu *= (1.0f / (E));                                            \
            float var = 0.f;                                               \
            _Pragma("unroll")                                              \
            for (int i = 0; i < (E); ++i) {                                \
                float d = y[(S) + i] - mu; var = fmaf(d, d, var);          \
            }                                                              \
            var *= (1.0f / (E));                                           \
            float rs = rsqrtf(var + LN_EPS);                               \
            _Pragma("unroll")                                              \
            for (int i = 0; i < (E); ++i) {                                \
                float nv = (y[(S) + i] - mu) * rs;                         \
                res[(S) + i] = fmaf(nv, ws[WS_G + (S) + i],                \
                                    ws[WS_BETA + (S) + i]);                \
            }                                                              \
        }
        LN_SEG(0, CXR)
        LN_SEG(CXR, ECG)
        LN_SEG(CXR + ECG, EHR)
#undef LN_SEG
    }
#pragma unroll
    for (int j = 0; j < CXR; ++j) af[S0F + lane * CXR + j] = res[j];
#pragma unroll
    for (int j = 0; j < ECG; ++j) af[S1F + lane * ECG + j] = res[CXR + j];
#pragma unroll
    for (int j = 0; j < EHR; ++j) af[S2F + lane * EHR + j] = res[CXR + ECG + j];
    __builtin_amdgcn_sched_barrier(0);

    // ---- coalesced float4 stores ----
    const float4v* wb4 = (const float4v*)af;
    float4v* o0 = (float4v*)(out_cxr + gw * (size_t)(WROWS * CXR));
    float4v* o1 = (float4v*)(out_ecg + gw * (size_t)(WROWS * ECG));
    float4v* o2 = (float4v*)(out_ehr + gw * (size_t)(WROWS * EHR));
#pragma unroll
    for (int it = 0; it < 4; ++it) {
        int idx = lane + it * 64;
        if (idx < WC0) o0[idx] = wb4[idx];
    }
#pragma unroll
    for (int it = 0; it < 4; ++it) {
        int idx = lane + it * 64;
        if (idx < WC1) o1[idx] = wb4[WC0 + idx];
    }
#pragma unroll
    for (int it = 0; it < 4; ++it) {
        int idx = lane + it * 64;
        if (idx < WC2) o2[idx] = wb4[WC0 + WC1 + idx];
    }
}

extern "C" void kernel_launch(void* const* d_in, const int* in_sizes, int n_in,
                              void* d_out, int out_size, void* d_ws, size_t ws_size,
                              hipStream_t stream) {
    const float* cxr = (const float*)d_in[0];
    const float* ecg = (const float*)d_in[1];
    const float* ehr = (const float*)d_in[2];
    float* ws = (float*)d_ws;
    float* out = (float*)d_out;

    const size_t Bn = (size_t)in_sizes[0] / CXR;   // 2097152

    auto mk = [&](int base, int E, int R) {
        FuseArgs a;
        a.in_w  = (const float*)d_in[base + 0];
        a.in_b  = (const float*)d_in[base + 1];
        a.out_w = (const float*)d_in[base + 2];
        a.out_b = (const float*)d_in[base + 3];
        a.kv_w  = (const float*)d_in[base + 4];
        a.kv_b  = (const float*)d_in[base + 5];
        a.ln_g  = (const float*)d_in[base + 6];
        a.ln_b  = (const float*)d_in[base + 7];
        a.E = E; a.R = R;
        return a;
    };
    FuseArgs a0 = mk(3, CXR, 0);
    FuseArgs a1 = mk(11, ECG, CXR);
    FuseArgs a2 = mk(19, EHR, CXR + ECG);

    fuse_all_kernel<<<3, 256, 0, stream>>>(a0, a1, a2, ws);

    const int nblocks = (int)(Bn / (WROWS * 2));   // 16384 blocks x 2 waves
    cmca_main<<<nblocks, 128, 0, stream>>>(cxr, ecg, ehr, ws,
                                           out,
                                           out + Bn * CXR,
                                           out + Bn * (CXR + ECG));
}